// Round 8
// baseline (563.126 us; speedup 1.0000x reference)
//
#include <hip/hip_runtime.h>

#define NN 100000
#define NE 1600000
#define DD 64
#define BSH 9
#define BSZ 512                          // nodes per bucket
#define NBKT 196                         // ceil(NN/512)
#define CHUNK 8192                       // edges per scatter block
#define NCH ((NE + CHUNK - 1) / CHUNK)   // 196
#define NGRP (NN / 8)                    // 12500 rank-groups of 8
#define SLS ((size_t)(NN + 1) * 8)       // floats per feature-slice (+1 dummy row)
#define CSRT_CAP 4000000
#define GPT 49                           // 256*49 >= NGRP

// ---------------- zero init (replaces memsets) ----------------

__global__ void k_zero(int* __restrict__ bcnt, float* __restrict__ h2sS) {
    int t = threadIdx.x;
    if (t < NBKT) bcnt[t] = 0;
    if (t < 64) h2sS[(size_t)(t >> 3) * SLS + (size_t)NN * 8 + (t & 7)] = 0.f;  // dummy rows
}

// ---------------- P1: coarse bucket histogram ----------------

__global__ __launch_bounds__(256) void k_bcount(const int* __restrict__ ei,
                                                int* __restrict__ bcnt) {
    __shared__ int h[NBKT];
    int t = threadIdx.x;
    for (int i = t; i < NBKT; i += 256) h[i] = 0;
    __syncthreads();
    int base = blockIdx.x * CHUNK;
    for (int i = t; i < CHUNK; i += 256) {
        int e = base + i;
        if (e < NE) atomicAdd(&h[ei[NE + e] >> BSH], 1);
    }
    __syncthreads();
    for (int i = t; i < NBKT; i += 256)
        if (h[i]) atomicAdd(&bcnt[i], h[i]);
}

// ---------------- P1s: parallel scan of bucket counts ----------------

__global__ __launch_bounds__(256) void k_bscan(const int* __restrict__ bcnt,
                                               int* __restrict__ bbase,
                                               int* __restrict__ bcur) {
    __shared__ int s[256];
    int t = threadIdx.x;
    int v = (t < NBKT) ? bcnt[t] : 0;
    s[t] = v;
    __syncthreads();
    for (int o = 1; o < 256; o <<= 1) {
        int x = (t >= o) ? s[t - o] : 0;
        __syncthreads();
        s[t] += x;
        __syncthreads();
    }
    int ex = s[t] - v;
    if (t < NBKT) { bbase[t] = ex; bcur[t] = ex; }
    if (t == NBKT) bbase[NBKT] = ex;
}

// ---------------- P2: scatter edges into bucket-grouped packed lists ----------------
// packed = s | (dlocal << 17);  s < 2^17, dlocal < 512.

__global__ __launch_bounds__(256) void k_bscat(const int* __restrict__ ei,
                                               int* __restrict__ bcur,
                                               int* __restrict__ bkt) {
    __shared__ int h[NBKT], rbase[NBKT], rcur[NBKT];
    int t = threadIdx.x;
    for (int i = t; i < NBKT; i += 256) h[i] = 0;
    __syncthreads();
    int cb = blockIdx.x * CHUNK;
    int s[32], d[32];
#pragma unroll
    for (int i = 0; i < 32; ++i) {
        int e = cb + t + 256 * i;
        if (e < NE) {
            s[i] = ei[e];
            d[i] = ei[NE + e];
            atomicAdd(&h[d[i] >> BSH], 1);
        } else {
            d[i] = -1;
        }
    }
    __syncthreads();
    for (int i = t; i < NBKT; i += 256) {
        int c = h[i];
        rbase[i] = c ? atomicAdd(&bcur[i], c) : 0;
        rcur[i] = 0;
    }
    __syncthreads();
#pragma unroll
    for (int i = 0; i < 32; ++i) {
        if (d[i] >= 0) {
            int b = d[i] >> BSH;
            int pos = rbase[b] + atomicAdd(&rcur[b], 1);
            bkt[pos] = s[i] | ((d[i] & (BSZ - 1)) << 17);
        }
    }
}

// ---------------- P3: per-bucket degree count + LDS counting-sort by degree ----------------
// rank space is dense: bucket b owns ranks [512b, 512b+count). Emits perm/invp/disP/pdegP.

__global__ __launch_bounds__(256) void k_sort(const int* __restrict__ bbase,
                                              const int* __restrict__ bkt,
                                              int* __restrict__ perm,
                                              int* __restrict__ invp,
                                              double* __restrict__ disP,
                                              int* __restrict__ pdegP) {
    __shared__ int cnt[BSZ];
    __shared__ int bins[256], binb[256], bcur2[256];
    int b = blockIdx.x, t = threadIdx.x;
    cnt[t] = 0; cnt[t + 256] = 0;
    bins[t] = 0;
    __syncthreads();
    int beg = bbase[b], end = bbase[b + 1];
    for (int j = beg + t; j < end; j += 256)
        atomicAdd(&cnt[bkt[j] >> 17], 1);
    __syncthreads();
    int nb = b * BSZ;
#pragma unroll
    for (int u = 0; u < 2; ++u) {
        int d = t + 256 * u;
        if (nb + d < NN) atomicAdd(&bins[min(cnt[d], 255)], 1);
    }
    __syncthreads();
    int v = bins[t];
    binb[t] = v;
    __syncthreads();
    for (int o = 1; o < 256; o <<= 1) {          // inclusive scan
        int x = (t >= o) ? binb[t - o] : 0;
        __syncthreads();
        binb[t] += x;
        __syncthreads();
    }
    int ex = binb[t] - v;                        // exclusive
    __syncthreads();
    binb[t] = ex;
    bcur2[t] = 0;
    __syncthreads();
#pragma unroll
    for (int u = 0; u < 2; ++u) {
        int d = t + 256 * u;
        int node = nb + d;
        if (node < NN) {
            int c = cnt[d];
            int bin = min(c, 255);
            int lr = binb[bin] + atomicAdd(&bcur2[bin], 1);
            int r = nb + lr;
            perm[r] = node;
            invp[node] = r;
            disP[r] = 1.0 / sqrt((double)(c + 1));
            pdegP[r] = c + 1;                    // entries incl. self
        }
    }
}

// ---------------- P4: group lengths (slots padded to multiple of 4), in int units ----------------

__global__ __launch_bounds__(256) void k_glen(const int* __restrict__ pdegP,
                                              int* __restrict__ glen8) {
    int g = blockIdx.x * 256 + threadIdx.x;
    if (g < NGRP) {
        int m = 0;
#pragma unroll
        for (int i = 0; i < 8; ++i) m = max(m, pdegP[g * 8 + i]);
        int slots = (m + 3) & ~3;                // multiple of 4 slots
        glen8[g] = slots * 8;                    // ints per group block
    }
}

// ---------------- P5: scan group lengths -> gbase ----------------

__global__ __launch_bounds__(256) void k_gscan(const int* __restrict__ glen8,
                                               int* __restrict__ gbase) {
    __shared__ int s[256];
    int t = threadIdx.x;
    int base = t * GPT;
    int sum = 0;
    for (int i = 0; i < GPT; ++i) {
        int g = base + i;
        if (g < NGRP) sum += glen8[g];
    }
    s[t] = sum;
    __syncthreads();
    for (int o = 1; o < 256; o <<= 1) {
        int x = (t >= o) ? s[t - o] : 0;
        __syncthreads();
        s[t] += x;
        __syncthreads();
    }
    int run = s[t] - sum;
    for (int i = 0; i < GPT; ++i) {
        int g = base + i;
        if (g < NGRP) { gbase[g] = run; run += glen8[g]; }
    }
    if (t == 255) gbase[NGRP] = s[255];
}

// ---------------- P6: build transposed ELL (csrT[gbase[g] + slot*8 + member]) ----------------

__global__ __launch_bounds__(256) void k_ell(const int* __restrict__ bbase,
                                             const int* __restrict__ bkt,
                                             const int* __restrict__ invp,
                                             const int* __restrict__ gbase,
                                             int* __restrict__ csrT) {
    __shared__ int cur[BSZ];
    __shared__ int eb8[BSZ];
    __shared__ int gl[BSZ];
    int b = blockIdx.x, t = threadIdx.x;
    int nb = b * BSZ;
#pragma unroll
    for (int u = 0; u < 2; ++u) {
        int d = t + 256 * u;
        int node = nb + d;
        if (node < NN) {
            int r = invp[node];
            int g = r >> 3;
            int e0 = gbase[g];
            int e = e0 + (r & 7);
            eb8[d] = e;
            gl[d] = (gbase[g + 1] - e0) >> 3;    // slot count
            csrT[e] = r;                         // self at slot 0 (rank index)
            cur[d] = 1;
        }
    }
    __syncthreads();
    int beg = bbase[b], end = bbase[b + 1];
    for (int j = beg + t; j < end; j += 256) {
        int pk = bkt[j];
        int dl = pk >> 17;
        int sl = atomicAdd(&cur[dl], 1);
        csrT[eb8[dl] + sl * 8] = invp[pk & 0x1FFFF];
    }
    __syncthreads();
#pragma unroll
    for (int u = 0; u < 2; ++u) {
        int d = t + 256 * u;
        if (nb + d < NN) {
            int e = eb8[d];
            int ge = gl[d];
            for (int j = cur[d]; j < ge; ++j) csrT[e + j * 8] = NN;  // dummy rank
        }
    }
}

// ---------------- h2sS[slice][rank][8] = (in @ W) * disP[rank] ----------------

__global__ __launch_bounds__(256) void k_gemm(const float* __restrict__ in,
                                              const int* __restrict__ perm,
                                              int sliced_in,
                                              const float* __restrict__ W,
                                              const double* __restrict__ disP,
                                              float* __restrict__ h2sS) {
    __shared__ float sW[DD * DD];
    __shared__ float sIn[128 * 65];
    __shared__ int sPerm[128];
    int t = threadIdx.x;
    int brow = blockIdx.x * 128;
    if (!sliced_in && t < 128) sPerm[t] = perm[min(brow + t, NN - 1)];
#pragma unroll
    for (int i = 0; i < 16; ++i) sW[t + 256 * i] = W[t + 256 * i];
    __syncthreads();
#pragma unroll
    for (int i = 0; i < 32; ++i) {
        int idx = t + 256 * i;
        int rr = idx >> 6, kk = idx & 63;
        float v;
        if (sliced_in) {
            int row = min(brow + rr, NN - 1);
            v = in[(size_t)(kk >> 3) * SLS + (size_t)row * 8 + (kk & 7)];
        } else {
            v = in[(size_t)sPerm[rr] * DD + kk];
        }
        sIn[rr * 65 + kk] = v;
    }
    __syncthreads();
    int cg = t & 7;
    int rg = t >> 3;
    const float* sInB = &sIn[rg * 4 * 65];

    float aE[4][8], aO[4][8];
#pragma unroll
    for (int i = 0; i < 4; ++i)
#pragma unroll
        for (int j = 0; j < 8; ++j) { aE[i][j] = 0.f; aO[i][j] = 0.f; }

#pragma unroll 4
    for (int k = 0; k < DD; k += 2) {
        float4 w0 = *(const float4*)&sW[k * DD + cg * 8];
        float4 w1 = *(const float4*)&sW[k * DD + cg * 8 + 4];
        float4 w2 = *(const float4*)&sW[(k + 1) * DD + cg * 8];
        float4 w3 = *(const float4*)&sW[(k + 1) * DD + cg * 8 + 4];
        float wv0[8] = {w0.x, w0.y, w0.z, w0.w, w1.x, w1.y, w1.z, w1.w};
        float wv1[8] = {w2.x, w2.y, w2.z, w2.w, w3.x, w3.y, w3.z, w3.w};
#pragma unroll
        for (int i = 0; i < 4; ++i) {
            float a0 = sInB[i * 65 + k];
            float a1 = sInB[i * 65 + k + 1];
#pragma unroll
            for (int j = 0; j < 8; ++j) {
                aE[i][j] = fmaf(a0, wv0[j], aE[i][j]);
                aO[i][j] = fmaf(a1, wv1[j], aO[i][j]);
            }
        }
    }

#pragma unroll
    for (int i = 0; i < 4; ++i) {
        int row = brow + rg * 4 + i;
        if (row < NN) {
            double dr = disP[row];
            float o[8];
#pragma unroll
            for (int j = 0; j < 8; ++j)
                o[j] = (float)((double)(aE[i][j] + aO[i][j]) * dr);
            *(float4*)&h2sS[(size_t)cg * SLS + (size_t)row * 8]     = make_float4(o[0], o[1], o[2], o[3]);
            *(float4*)&h2sS[(size_t)cg * SLS + (size_t)row * 8 + 4] = make_float4(o[4], o[5], o[6], o[7]);
        }
    }
}

// ---------------- aggregate: slice = blockIdx%8 (XCD-affine), wave = 8 ranks x 8 feats ----------------

__global__ __launch_bounds__(256) void k_aggr(const int* __restrict__ gbase,
                                              const int* __restrict__ csrT,
                                              const float* __restrict__ h2sS,
                                              const double* __restrict__ disP,
                                              const int* __restrict__ perm,
                                              const float* __restrict__ bias,
                                              float* __restrict__ outp,
                                              int apply_elu, int out_node_major) {
    int t = threadIdx.x;
    int lane = t & 63;
    int wid = __builtin_amdgcn_readfirstlane(t >> 6);
    int s = blockIdx.x & 7;
    int g = (blockIdx.x >> 3) * 4 + wid;       // < NGRP exactly
    int n = lane >> 3, f = lane & 7;
    int r = g * 8 + n;
    int e0 = __builtin_amdgcn_readfirstlane(gbase[g]);
    int e1 = __builtin_amdgcn_readfirstlane(gbase[g + 1]);
    const float* sb = h2sS + (size_t)s * SLS;
    double dn = disP[r];
    float bv = bias[s * 8 + f];
    double acc = 0.0;
    for (int off = e0; off < e1; off += 32) {  // 4 slots per iteration
        int i0 = csrT[off + n];
        int i1 = csrT[off + 8 + n];
        int i2 = csrT[off + 16 + n];
        int i3 = csrT[off + 24 + n];
        float v0 = sb[(size_t)(unsigned)i0 * 8 + f];
        float v1 = sb[(size_t)(unsigned)i1 * 8 + f];
        float v2 = sb[(size_t)(unsigned)i2 * 8 + f];
        float v3 = sb[(size_t)(unsigned)i3 * 8 + f];
        acc += (double)v0;
        acc += (double)v1;
        acc += (double)v2;
        acc += (double)v3;
    }
    float vf = (float)(dn * acc + (double)bv);
    if (apply_elu && vf <= 0.f) vf = expm1f(vf);
    if (out_node_major) outp[(size_t)perm[r] * DD + s * 8 + f] = vf;
    else                outp[(size_t)s * SLS + (size_t)r * 8 + f] = vf;
}

// ---------------- launch ----------------

static inline size_t align256(size_t x) { return (x + 255) & ~(size_t)255; }

extern "C" void kernel_launch(void* const* d_in, const int* in_sizes, int n_in,
                              void* d_out, int out_size, void* d_ws, size_t ws_size,
                              hipStream_t stream) {
    const float* x  = (const float*)d_in[0];
    const int*   ei = (const int*)d_in[1];
    const float* W1 = (const float*)d_in[3];
    const float* b1 = (const float*)d_in[4];
    const float* W2 = (const float*)d_in[5];
    const float* b2 = (const float*)d_in[6];
    const float* W3 = (const float*)d_in[7];
    const float* b3 = (const float*)d_in[8];
    const float* W4 = (const float*)d_in[9];
    const float* b4 = (const float*)d_in[10];
    float* out = (float*)d_out;

    char* ws = (char*)d_ws;
    size_t off = 0;
    float*  h2sS  = (float*) (ws + off); off = align256(off + 8 * SLS * sizeof(float));      // 25.6 MB
    float*  AS    = (float*) (ws + off); off = align256(off + 8 * SLS * sizeof(float));      // 25.6 MB
    double* disP  = (double*)(ws + off); off = align256(off + (size_t)NN * sizeof(double));
    int*    perm  = (int*)   (ws + off); off = align256(off + (size_t)NN * sizeof(int));
    int*    invp  = (int*)   (ws + off); off = align256(off + (size_t)NN * sizeof(int));
    int*    pdegP = (int*)   (ws + off); off = align256(off + (size_t)NN * sizeof(int));
    int*    glen8 = (int*)   (ws + off); off = align256(off + (size_t)NGRP * sizeof(int));
    int*    gbase = (int*)   (ws + off); off = align256(off + (size_t)(NGRP + 1) * sizeof(int));
    int*    bcnt  = (int*)   (ws + off); off = align256(off + (size_t)(NBKT + 1) * sizeof(int));
    int*    bbase = (int*)   (ws + off); off = align256(off + (size_t)(NBKT + 1) * sizeof(int));
    int*    bcur  = (int*)   (ws + off); off = align256(off + (size_t)(NBKT + 1) * sizeof(int));
    int*    bkt   = (int*)   (ws + off); off = align256(off + (size_t)NE * sizeof(int));     // 6.4 MB
    int*    csrT  = (int*)   (ws + off); off = align256(off + (size_t)CSRT_CAP * sizeof(int)); // 16 MB

    k_zero<<<1, 256, 0, stream>>>(bcnt, h2sS);
    k_bcount<<<NCH, 256, 0, stream>>>(ei, bcnt);
    k_bscan<<<1, 256, 0, stream>>>(bcnt, bbase, bcur);
    k_bscat<<<NCH, 256, 0, stream>>>(ei, bcur, bkt);
    k_sort<<<NBKT, 256, 0, stream>>>(bbase, bkt, perm, invp, disP, pdegP);
    k_glen<<<(NGRP + 255) / 256, 256, 0, stream>>>(pdegP, glen8);
    k_gscan<<<1, 256, 0, stream>>>(glen8, gbase);
    k_ell<<<NBKT, 256, 0, stream>>>(bbase, bkt, invp, gbase, csrT);

    struct Layer { const float* in; int sliced; const float* W; const float* b;
                   float* o; int elu; int nodemaj; };
    Layer L[4] = {
        { x,  0, W1, b1, AS,  1, 0 },
        { AS, 1, W2, b2, AS,  1, 0 },
        { AS, 1, W3, b3, AS,  1, 0 },
        { AS, 1, W4, b4, out, 0, 1 },
    };

    for (int l = 0; l < 4; ++l) {
        k_gemm<<<(NN + 127) / 128, 256, 0, stream>>>(L[l].in, perm, L[l].sliced,
                                                     L[l].W, disP, h2sS);
        k_aggr<<<(NGRP / 4) * 8, 256, 0, stream>>>(gbase, csrT, h2sS, disP, perm,
                                                   L[l].b, L[l].o, L[l].elu, L[l].nodemaj);
    }
}

// Round 9
// 448.360 us; speedup vs baseline: 1.2560x; 1.2560x over previous
//
#include <hip/hip_runtime.h>

#define NN 100000
#define NE 1600000
#define DD 64
#define BSH 9
#define BSZ 512                          // nodes per bucket
#define NBKT 196                         // ceil(NN/512)
#define CHUNK 8192                       // edges per scatter block
#define NCH ((NE + CHUNK - 1) / CHUNK)   // 196
#define CSR2_CAP (NE + 8 * NN + 64)      // sum of pad8(deg+1)

// ---------------- zero init ----------------

__global__ void k_zero(int* __restrict__ bcnt, float* __restrict__ h2s) {
    int t = threadIdx.x;
    if (t < NBKT) bcnt[t] = 0;
    if (t < DD) h2s[(size_t)NN * DD + t] = 0.f;   // dummy rank row = 0
}

// ---------------- P1: coarse bucket histogram ----------------

__global__ __launch_bounds__(256) void k_bcount(const int* __restrict__ ei,
                                                int* __restrict__ bcnt) {
    __shared__ int h[NBKT];
    int t = threadIdx.x;
    for (int i = t; i < NBKT; i += 256) h[i] = 0;
    __syncthreads();
    int base = blockIdx.x * CHUNK;
    for (int i = t; i < CHUNK; i += 256) {
        int e = base + i;
        if (e < NE) atomicAdd(&h[ei[NE + e] >> BSH], 1);
    }
    __syncthreads();
    for (int i = t; i < NBKT; i += 256)
        if (h[i]) atomicAdd(&bcnt[i], h[i]);
}

// ---------------- P1s: parallel scan of bucket counts ----------------

__global__ __launch_bounds__(256) void k_bscan(const int* __restrict__ bcnt,
                                               int* __restrict__ bbase,
                                               int* __restrict__ bcur) {
    __shared__ int s[256];
    int t = threadIdx.x;
    int v = (t < NBKT) ? bcnt[t] : 0;
    s[t] = v;
    __syncthreads();
    for (int o = 1; o < 256; o <<= 1) {
        int x = (t >= o) ? s[t - o] : 0;
        __syncthreads();
        s[t] += x;
        __syncthreads();
    }
    int ex = s[t] - v;
    if (t < NBKT) { bbase[t] = ex; bcur[t] = ex; }
    if (t == NBKT) bbase[NBKT] = ex;
}

// ---------------- P2: scatter edges into bucket-grouped packed lists ----------------
// packed = s | (dlocal << 17);  s < 2^17, dlocal < 512.

__global__ __launch_bounds__(256) void k_bscat(const int* __restrict__ ei,
                                               int* __restrict__ bcur,
                                               int* __restrict__ bkt) {
    __shared__ int h[NBKT], rbase[NBKT], rcur[NBKT];
    int t = threadIdx.x;
    for (int i = t; i < NBKT; i += 256) h[i] = 0;
    __syncthreads();
    int cb = blockIdx.x * CHUNK;
    int s[32], d[32];
#pragma unroll
    for (int i = 0; i < 32; ++i) {
        int e = cb + t + 256 * i;
        if (e < NE) {
            s[i] = ei[e];
            d[i] = ei[NE + e];
            atomicAdd(&h[d[i] >> BSH], 1);
        } else {
            d[i] = -1;
        }
    }
    __syncthreads();
    for (int i = t; i < NBKT; i += 256) {
        int c = h[i];
        rbase[i] = c ? atomicAdd(&bcur[i], c) : 0;
        rcur[i] = 0;
    }
    __syncthreads();
#pragma unroll
    for (int i = 0; i < 32; ++i) {
        if (d[i] >= 0) {
            int b = d[i] >> BSH;
            int pos = rbase[b] + atomicAdd(&rcur[b], 1);
            bkt[pos] = s[i] | ((d[i] & (BSZ - 1)) << 17);
        }
    }
}

// ---------------- P3: per-bucket degree count + LDS counting-sort by degree ----------------
// ranks are dense and degree-sorted within each bucket. Emits perm/invp/disP/pdegP/bptot.

__global__ __launch_bounds__(256) void k_sort(const int* __restrict__ bbase,
                                              const int* __restrict__ bkt,
                                              int* __restrict__ perm,
                                              int* __restrict__ invp,
                                              double* __restrict__ disP,
                                              int* __restrict__ pdegP,
                                              int* __restrict__ bptot) {
    __shared__ int cnt[BSZ];
    __shared__ int bins[256], binb[256], bcur2[256], red[256];
    int b = blockIdx.x, t = threadIdx.x;
    cnt[t] = 0; cnt[t + 256] = 0;
    bins[t] = 0;
    __syncthreads();
    int beg = bbase[b], end = bbase[b + 1];
    for (int j = beg + t; j < end; j += 256)
        atomicAdd(&cnt[bkt[j] >> 17], 1);
    __syncthreads();
    int nb = b * BSZ;
    int padsum = 0;
#pragma unroll
    for (int u = 0; u < 2; ++u) {
        int d = t + 256 * u;
        if (nb + d < NN) {
            atomicAdd(&bins[min(cnt[d], 255)], 1);
            padsum += (cnt[d] + 8) & ~7;          // pad8(deg+1)
        }
    }
    red[t] = padsum;
    __syncthreads();
    int v = bins[t];
    binb[t] = v;
    __syncthreads();
    for (int o = 1; o < 256; o <<= 1) {          // inclusive scan of degree bins
        int x = (t >= o) ? binb[t - o] : 0;
        __syncthreads();
        binb[t] += x;
        __syncthreads();
    }
    int ex = binb[t] - v;
    __syncthreads();
    binb[t] = ex;
    bcur2[t] = 0;
    __syncthreads();
#pragma unroll
    for (int u = 0; u < 2; ++u) {
        int d = t + 256 * u;
        int node = nb + d;
        if (node < NN) {
            int c = cnt[d];
            int bin = min(c, 255);
            int lr = binb[bin] + atomicAdd(&bcur2[bin], 1);
            int r = nb + lr;
            perm[r] = node;
            invp[node] = r;
            disP[r] = 1.0 / sqrt((double)(c + 1));
            pdegP[r] = c + 1;                    // entries incl. self
        }
    }
    // reduce padded totals
    __syncthreads();
    for (int o = 128; o > 0; o >>= 1) {
        if (t < o) red[t] += red[t + o];
        __syncthreads();
    }
    if (t == 0) bptot[b] = red[0];
}

// ---------------- P4: parallel scan of padded bucket totals ----------------

__global__ __launch_bounds__(256) void k_pscan(const int* __restrict__ bptot,
                                               int* __restrict__ pbase,
                                               int* __restrict__ rp2) {
    __shared__ int s[256];
    int t = threadIdx.x;
    int v = (t < NBKT) ? bptot[t] : 0;
    s[t] = v;
    __syncthreads();
    for (int o = 1; o < 256; o <<= 1) {
        int x = (t >= o) ? s[t - o] : 0;
        __syncthreads();
        s[t] += x;
        __syncthreads();
    }
    int ex = s[t] - v;
    if (t < NBKT) pbase[t] = ex;
    if (t == NBKT) rp2[NN] = ex;
}

// ---------------- P5: per-bucket rp2 + csr2 fill in RANK space ----------------

__global__ __launch_bounds__(256) void k_bfill(const int* __restrict__ bbase,
                                               const int* __restrict__ bkt,
                                               const int* __restrict__ pdegP,
                                               const int* __restrict__ pbase,
                                               const int* __restrict__ invp,
                                               int* __restrict__ rp2,
                                               int* __restrict__ csr2) {
    __shared__ int cur[BSZ];
    __shared__ int lrOf[BSZ];
    __shared__ int s2[256];
    int b = blockIdx.x, t = threadIdx.x;
    int nb = b * BSZ;
    int gbase = pbase[b];
    // node-local -> rank-local translation table
#pragma unroll
    for (int u = 0; u < 2; ++u) {
        int d = t + 256 * u;
        if (nb + d < NN) lrOf[d] = invp[nb + d] - nb;
    }
    int r0 = nb + 2 * t, r1 = nb + 2 * t + 1;
    int p0 = (r0 < NN) ? pdegP[r0] : -1;         // deg+1
    int p1 = (r1 < NN) ? pdegP[r1] : -1;
    int q0 = (p0 >= 0) ? ((p0 + 7) & ~7) : 0;
    int q1 = (p1 >= 0) ? ((p1 + 7) & ~7) : 0;
    s2[t] = q0 + q1;
    __syncthreads();
    for (int o = 1; o < 256; o <<= 1) {          // Hillis-Steele inclusive scan
        int v = (t >= o) ? s2[t - o] : 0;
        __syncthreads();
        s2[t] += v;
        __syncthreads();
    }
    int ex = s2[t] - (q0 + q1);                  // exclusive offset of rank r0
    if (p0 >= 0) { int g = gbase + ex;      rp2[r0] = g; csr2[g] = r0; cur[2 * t]     = ex + 1; }
    if (p1 >= 0) { int g = gbase + ex + q0; rp2[r1] = g; csr2[g] = r1; cur[2 * t + 1] = ex + q0 + 1; }
    __syncthreads();
    int beg = bbase[b], end = bbase[b + 1];
    for (int j = beg + t; j < end; j += 256) {
        int pk = bkt[j];
        int lr = lrOf[pk >> 17];
        int pos = gbase + atomicAdd(&cur[lr], 1);
        csr2[pos] = invp[pk & 0x1FFFF];          // src rank
    }
    __syncthreads();
    if (p0 >= 0) { int e0 = ex + q0;      for (int j = cur[2 * t];     j < e0; ++j) csr2[gbase + j] = NN; }
    if (p1 >= 0) { int e1 = ex + q0 + q1; for (int j = cur[2 * t + 1]; j < e1; ++j) csr2[gbase + j] = NN; }
}

// ---------------- h2s[rank][64] = (in @ W) * disP[rank] ----------------

__global__ __launch_bounds__(256) void k_gemm(const float* __restrict__ in,
                                              const int* __restrict__ perm,
                                              int permuted_in,
                                              const float* __restrict__ W,
                                              const double* __restrict__ disP,
                                              float* __restrict__ h2s) {
    __shared__ float sW[DD * DD];
    __shared__ float sIn[128 * 65];
    __shared__ int sPerm[128];
    int t = threadIdx.x;
    int brow = blockIdx.x * 128;
    if (permuted_in && t < 128) sPerm[t] = perm[min(brow + t, NN - 1)];
#pragma unroll
    for (int i = 0; i < 16; ++i) sW[t + 256 * i] = W[t + 256 * i];
    __syncthreads();
#pragma unroll
    for (int i = 0; i < 32; ++i) {
        int idx = t + 256 * i;
        int rr = idx >> 6, kk = idx & 63;
        float v;
        if (permuted_in) {
            v = in[(size_t)sPerm[rr] * DD + kk];
        } else {
            int row = min(brow + rr, NN - 1);
            v = in[(size_t)row * DD + kk];
        }
        sIn[rr * 65 + kk] = v;
    }
    __syncthreads();
    int cg = t & 7;
    int rg = t >> 3;
    const float* sInB = &sIn[rg * 4 * 65];

    float aE[4][8], aO[4][8];
#pragma unroll
    for (int i = 0; i < 4; ++i)
#pragma unroll
        for (int j = 0; j < 8; ++j) { aE[i][j] = 0.f; aO[i][j] = 0.f; }

#pragma unroll 4
    for (int k = 0; k < DD; k += 2) {
        float4 w0 = *(const float4*)&sW[k * DD + cg * 8];
        float4 w1 = *(const float4*)&sW[k * DD + cg * 8 + 4];
        float4 w2 = *(const float4*)&sW[(k + 1) * DD + cg * 8];
        float4 w3 = *(const float4*)&sW[(k + 1) * DD + cg * 8 + 4];
        float wv0[8] = {w0.x, w0.y, w0.z, w0.w, w1.x, w1.y, w1.z, w1.w};
        float wv1[8] = {w2.x, w2.y, w2.z, w2.w, w3.x, w3.y, w3.z, w3.w};
#pragma unroll
        for (int i = 0; i < 4; ++i) {
            float a0 = sInB[i * 65 + k];
            float a1 = sInB[i * 65 + k + 1];
#pragma unroll
            for (int j = 0; j < 8; ++j) {
                aE[i][j] = fmaf(a0, wv0[j], aE[i][j]);
                aO[i][j] = fmaf(a1, wv1[j], aO[i][j]);
            }
        }
    }

#pragma unroll
    for (int i = 0; i < 4; ++i) {
        int row = brow + rg * 4 + i;
        if (row < NN) {
            double dr = disP[row];
            float o[8];
#pragma unroll
            for (int j = 0; j < 8; ++j)
                o[j] = (float)((double)(aE[i][j] + aO[i][j]) * dr);
            *(float4*)&h2s[(size_t)row * DD + cg * 8]     = make_float4(o[0], o[1], o[2], o[3]);
            *(float4*)&h2s[(size_t)row * DD + cg * 8 + 4] = make_float4(o[4], o[5], o[6], o[7]);
        }
    }
}

// ---------------- gather-aggregate: lane = feature, degree-uniform blocks ----------------

__global__ __launch_bounds__(256) void k_aggr(const int* __restrict__ rp2,
                                              const int* __restrict__ csr2,
                                              const float* __restrict__ h2s,
                                              const double* __restrict__ disP,
                                              const int* __restrict__ perm,
                                              const float* __restrict__ bias,
                                              float* __restrict__ outp,
                                              int apply_elu, int out_node_major) {
    int gid = blockIdx.x * 256 + threadIdx.x;
    int r = gid >> 6;
    int lane = gid & 63;
    int beg = __builtin_amdgcn_readfirstlane(rp2[r]);
    int end = __builtin_amdgcn_readfirstlane(rp2[r + 1]);
    double a0 = 0.0, a1 = 0.0, a2 = 0.0, a3 = 0.0;
    int j = beg;
    for (; j + 16 <= end; j += 16) {
        int4 i0 = *(const int4*)&csr2[j];
        int4 i1 = *(const int4*)&csr2[j + 4];
        int4 i2 = *(const int4*)&csr2[j + 8];
        int4 i3 = *(const int4*)&csr2[j + 12];
        float v0  = h2s[(size_t)(unsigned)i0.x * DD + lane];
        float v1  = h2s[(size_t)(unsigned)i0.y * DD + lane];
        float v2  = h2s[(size_t)(unsigned)i0.z * DD + lane];
        float v3  = h2s[(size_t)(unsigned)i0.w * DD + lane];
        float v4  = h2s[(size_t)(unsigned)i1.x * DD + lane];
        float v5  = h2s[(size_t)(unsigned)i1.y * DD + lane];
        float v6  = h2s[(size_t)(unsigned)i1.z * DD + lane];
        float v7  = h2s[(size_t)(unsigned)i1.w * DD + lane];
        float v8  = h2s[(size_t)(unsigned)i2.x * DD + lane];
        float v9  = h2s[(size_t)(unsigned)i2.y * DD + lane];
        float v10 = h2s[(size_t)(unsigned)i2.z * DD + lane];
        float v11 = h2s[(size_t)(unsigned)i2.w * DD + lane];
        float v12 = h2s[(size_t)(unsigned)i3.x * DD + lane];
        float v13 = h2s[(size_t)(unsigned)i3.y * DD + lane];
        float v14 = h2s[(size_t)(unsigned)i3.z * DD + lane];
        float v15 = h2s[(size_t)(unsigned)i3.w * DD + lane];
        a0 += (double)v0;  a1 += (double)v1;  a2 += (double)v2;  a3 += (double)v3;
        a0 += (double)v4;  a1 += (double)v5;  a2 += (double)v6;  a3 += (double)v7;
        a0 += (double)v8;  a1 += (double)v9;  a2 += (double)v10; a3 += (double)v11;
        a0 += (double)v12; a1 += (double)v13; a2 += (double)v14; a3 += (double)v15;
    }
    if (j < end) {                               // exactly 8 remain (pad8)
        int4 i0 = *(const int4*)&csr2[j];
        int4 i1 = *(const int4*)&csr2[j + 4];
        float v0 = h2s[(size_t)(unsigned)i0.x * DD + lane];
        float v1 = h2s[(size_t)(unsigned)i0.y * DD + lane];
        float v2 = h2s[(size_t)(unsigned)i0.z * DD + lane];
        float v3 = h2s[(size_t)(unsigned)i0.w * DD + lane];
        float v4 = h2s[(size_t)(unsigned)i1.x * DD + lane];
        float v5 = h2s[(size_t)(unsigned)i1.y * DD + lane];
        float v6 = h2s[(size_t)(unsigned)i1.z * DD + lane];
        float v7 = h2s[(size_t)(unsigned)i1.w * DD + lane];
        a0 += (double)v0; a1 += (double)v1; a2 += (double)v2; a3 += (double)v3;
        a0 += (double)v4; a1 += (double)v5; a2 += (double)v6; a3 += (double)v7;
    }
    double sum = (a0 + a1) + (a2 + a3);
    float vf = (float)(disP[r] * sum + (double)bias[lane]);
    if (apply_elu && vf <= 0.f) vf = expm1f(vf);
    if (out_node_major) {
        int node = __builtin_amdgcn_readfirstlane(perm[r]);
        outp[(size_t)node * DD + lane] = vf;
    } else {
        outp[(size_t)r * DD + lane] = vf;
    }
}

// ---------------- launch ----------------

static inline size_t align256(size_t x) { return (x + 255) & ~(size_t)255; }

extern "C" void kernel_launch(void* const* d_in, const int* in_sizes, int n_in,
                              void* d_out, int out_size, void* d_ws, size_t ws_size,
                              hipStream_t stream) {
    const float* x  = (const float*)d_in[0];
    const int*   ei = (const int*)d_in[1];
    const float* W1 = (const float*)d_in[3];
    const float* b1 = (const float*)d_in[4];
    const float* W2 = (const float*)d_in[5];
    const float* b2 = (const float*)d_in[6];
    const float* W3 = (const float*)d_in[7];
    const float* b3 = (const float*)d_in[8];
    const float* W4 = (const float*)d_in[9];
    const float* b4 = (const float*)d_in[10];
    float* out = (float*)d_out;

    char* ws = (char*)d_ws;
    size_t off = 0;
    float*  h2s   = (float*) (ws + off); off = align256(off + (size_t)(NN + 1) * DD * sizeof(float));
    float*  A     = (float*) (ws + off); off = align256(off + (size_t)NN * DD * sizeof(float));
    double* disP  = (double*)(ws + off); off = align256(off + (size_t)NN * sizeof(double));
    int*    perm  = (int*)   (ws + off); off = align256(off + (size_t)NN * sizeof(int));
    int*    invp  = (int*)   (ws + off); off = align256(off + (size_t)NN * sizeof(int));
    int*    pdegP = (int*)   (ws + off); off = align256(off + (size_t)NN * sizeof(int));
    int*    rp2   = (int*)   (ws + off); off = align256(off + (size_t)(NN + 1) * sizeof(int));
    int*    bcnt  = (int*)   (ws + off); off = align256(off + (size_t)(NBKT + 1) * sizeof(int));
    int*    bbase = (int*)   (ws + off); off = align256(off + (size_t)(NBKT + 1) * sizeof(int));
    int*    bcur  = (int*)   (ws + off); off = align256(off + (size_t)(NBKT + 1) * sizeof(int));
    int*    bptot = (int*)   (ws + off); off = align256(off + (size_t)(NBKT + 1) * sizeof(int));
    int*    pbase = (int*)   (ws + off); off = align256(off + (size_t)(NBKT + 1) * sizeof(int));
    int*    bkt   = (int*)   (ws + off); off = align256(off + (size_t)NE * sizeof(int));
    int*    csr2  = (int*)   (ws + off); off = align256(off + (size_t)CSR2_CAP * sizeof(int));

    k_zero<<<1, 256, 0, stream>>>(bcnt, h2s);
    k_bcount<<<NCH, 256, 0, stream>>>(ei, bcnt);
    k_bscan<<<1, 256, 0, stream>>>(bcnt, bbase, bcur);
    k_bscat<<<NCH, 256, 0, stream>>>(ei, bcur, bkt);
    k_sort<<<NBKT, 256, 0, stream>>>(bbase, bkt, perm, invp, disP, pdegP, bptot);
    k_pscan<<<1, 256, 0, stream>>>(bptot, pbase, rp2);
    k_bfill<<<NBKT, 256, 0, stream>>>(bbase, bkt, pdegP, pbase, invp, rp2, csr2);

    struct Layer { const float* in; int permuted; const float* W; const float* b;
                   float* o; int elu; int nodemaj; };
    Layer L[4] = {
        { x, 1, W1, b1, A,   1, 0 },
        { A, 0, W2, b2, A,   1, 0 },
        { A, 0, W3, b3, A,   1, 0 },
        { A, 0, W4, b4, out, 0, 1 },
    };

    for (int l = 0; l < 4; ++l) {
        k_gemm<<<(NN + 127) / 128, 256, 0, stream>>>(L[l].in, perm, L[l].permuted,
                                                     L[l].W, disP, h2s);
        k_aggr<<<NN / 4, 256, 0, stream>>>(rp2, csr2, h2s, disP, perm,
                                           L[l].b, L[l].o, L[l].elu, L[l].nodemaj);
    }
}